// Round 15
// baseline (639.155 us; speedup 1.0000x reference)
//
#include <hip/hip_runtime.h>
#include <hip/hip_bf16.h>

// RotaryCrossAttention on MI355X (gfx950).
// v15 = v14 with k_attn occupancy unlock: 32-key steps (LDS 34KB -> 4
//      blocks/CU), kq=8 key-split (grid 1024 = 4 blocks/CU resident ->
//      8 waves/SIMD), AOp partials in bf16 (8 planes, same ws bytes).
//      Per-wave per-key work and total LDS traffic unchanged — pure
//      latency-hiding. fin1 merges 8 partials. kvproj = v11 exact.
// Pipeline: k_cvtw ; k_mask ; k_vrow ; k_stats ; k_qproj ; k_kvproj ;
//           k_attn ; k_fin1 ; k_fin2

#define DEV static __device__ __forceinline__

typedef __attribute__((ext_vector_type(4))) float f32x4;
typedef __attribute__((ext_vector_type(8))) short s16x8;
typedef __attribute__((ext_vector_type(4))) unsigned u32x4;

constexpr int NB   = 16;
constexpr int NQ   = 1024;
constexpr int SC   = 8192;   // T*C
constexpr int DIM  = 512;
constexpr int CDIM = 256;
constexpr int DH   = 128;
constexpr int VTR  = 144;    // V tile rows: d 0..127, row128 = mask-ones, 129..143 dead
constexpr int VTILE = VTR*64; // elems per 64-key V tile (18KB)
constexpr int NKQ  = 8;      // key splits

DEV short f2bf(float x){
  unsigned u = __builtin_bit_cast(unsigned, x);
  unsigned r = (u + 0x7FFFu + ((u >> 16) & 1u)) >> 16;
  return (short)r;
}

DEV float bf2f(short v){
  unsigned u = ((unsigned)(unsigned short)v) << 16;
  return __builtin_bit_cast(float, u);
}

DEV unsigned pk2(float a, float b){
  unsigned short ua = __builtin_bit_cast(unsigned short, __float2bfloat16(a));
  unsigned short ub = __builtin_bit_cast(unsigned short, __float2bfloat16(b));
  return (unsigned)ua | ((unsigned)ub << 16);
}

DEV f32x4 mfma16(s16x8 a, s16x8 b, f32x4 c){
  return __builtin_amdgcn_mfma_f32_16x16x32_bf16(a, b, c, 0, 0, 0);
}

DEV void gload16(const void* g, void* l){
  __builtin_amdgcn_global_load_lds(
      (const __attribute__((address_space(1))) void*)g,
      (__attribute__((address_space(3))) void*)l, 16, 0, 0);
}

// P cross-lane exchange (verified v3): C-layout St rows -> PV B-frag.
DEV s16x8 pexch(int ia0, int ia1, bool hi, unsigned L0, unsigned H0, unsigned L1, unsigned H1){
  int aL0 = __builtin_amdgcn_ds_bpermute(ia0, (int)L0);
  int aL1 = __builtin_amdgcn_ds_bpermute(ia0, (int)L1);
  int aH0 = __builtin_amdgcn_ds_bpermute(ia0, (int)H0);
  int aH1 = __builtin_amdgcn_ds_bpermute(ia0, (int)H1);
  int bL0 = __builtin_amdgcn_ds_bpermute(ia1, (int)L0);
  int bL1 = __builtin_amdgcn_ds_bpermute(ia1, (int)L1);
  int bH0 = __builtin_amdgcn_ds_bpermute(ia1, (int)H0);
  int bH1 = __builtin_amdgcn_ds_bpermute(ia1, (int)H1);
  u32x4 r;
  r[0] = (unsigned)(hi ? aL1 : aL0);
  r[1] = (unsigned)(hi ? aH1 : aH0);
  r[2] = (unsigned)(hi ? bL1 : bL0);
  r[3] = (unsigned)(hi ? bH1 : bH0);
  return __builtin_bit_cast(s16x8, r);
}

// ---------------- weights f32 -> bf16 ----------------
__global__ void k_cvtw(const float* __restrict__ wq, const float* __restrict__ wkv,
                       short* __restrict__ wqb, short* __restrict__ wkvb){
  int i = blockIdx.x * 256 + threadIdx.x;
  if(i < 128*512) wqb[i]  = f2bf(wq[i]);
  if(i < 256*256) wkvb[i] = f2bf(wkv[i]);
}

// ---------------- mask: detect bool(1B) vs int32(4B), pack to bits ----------------
__global__ void k_mask(const unsigned char* __restrict__ raw, unsigned* __restrict__ bits){
  const int b = blockIdx.x, t = threadIdx.x;
  int nz = 0;
  for(int i = t; i < 8192; i += 256){       // first 32KB valid under both layouts
    unsigned w = ((const unsigned*)raw)[i];
    if(w & 0xFFFFFF00u) nz = 1;
  }
  int any = __syncthreads_or(nz);
  bool isInt = (any == 0);
  if(t < 64){
    unsigned out = 0;
    if(isInt){
      const int* p = (const int*)raw + (b*2048 + t*32);
      for(int j = 0; j < 32; j++) out |= (unsigned)(p[j] != 0) << j;
    } else {
      const unsigned char* p = raw + (b*2048 + t*32);
      for(int j = 0; j < 32; j++) out |= (unsigned)(p[j] != 0) << j;
    }
    bits[b*64 + t] = out;
  }
}

// ---------------- V tile row 128 = mask as bf16 ones ----------------
__global__ void k_vrow(const unsigned* __restrict__ bits, short* __restrict__ Vt){
  int b = blockIdx.y;
  int s = blockIdx.x * 256 + threadIdx.x;    // 0..8191
  unsigned w = bits[b*64 + ((s & 2047) >> 5)];
  short v = ((w >> (s & 31)) & 1u) ? (short)0x3F80 : (short)0;
  Vt[(((size_t)b*128 + (s >> 6))*VTR + 128)*64 + (s & 63)] = v;
}

// ---------------- LN stats for context rows: mu/rstd per row ----------------
__global__ __launch_bounds__(256) void k_stats(const float* __restrict__ xc,
                                               float* __restrict__ MU, float* __restrict__ RS){
  const size_t row = (size_t)blockIdx.x * 16 + (threadIdx.x >> 4);   // global row in [0, NB*SC)
  const int cl = (threadIdx.x & 15) * 16;
  const float* rp = xc + row * CDIM + cl;
  float s = 0.f, sq = 0.f;
  #pragma unroll
  for(int i = 0; i < 4; i++){
    f32x4 a = *(const f32x4*)(rp + i*4);
    #pragma unroll
    for(int j = 0; j < 4; j++){ s += a[j]; sq += a[j]*a[j]; }
  }
  #pragma unroll
  for(int o = 8; o > 0; o >>= 1){ s += __shfl_xor(s, o); sq += __shfl_xor(sq, o); }
  if((threadIdx.x & 15) == 0){
    float m = s * (1.f/CDIM);
    MU[row] = m;
    RS[row] = rsqrtf(sq * (1.f/CDIM) - m*m + 1e-5f);
  }
}

// ---------------- Q projection: LN + GEMM (1024x512 @ 512x128) ----------------
__global__ __launch_bounds__(256) void k_qproj(const float* __restrict__ xq,
                                               const float* __restrict__ lnw, const float* __restrict__ lnb,
                                               const short* __restrict__ wqb, float* __restrict__ Q0){
  const int wid = threadIdx.x >> 6, lane = threadIdx.x & 63;
  const int g = lane >> 4, li = lane & 15;
  const int row0 = blockIdx.x * 64 + wid * 16;

  float mean = 0.f, rstd = 0.f;
  #pragma unroll
  for(int r = 0; r < 16; r++){
    const float* rp = xq + (row0 + r) * DIM;
    f32x4 a = *(const f32x4*)(rp + lane*8);
    f32x4 b = *(const f32x4*)(rp + lane*8 + 4);
    float s = 0.f, sq = 0.f;
    #pragma unroll
    for(int i = 0; i < 4; i++){ s += a[i] + b[i]; sq += a[i]*a[i] + b[i]*b[i]; }
    #pragma unroll
    for(int o = 32; o > 0; o >>= 1){ s += __shfl_xor(s, o); sq += __shfl_xor(sq, o); }
    if(li == r){
      mean = s / DIM;
      float var = sq / DIM - mean*mean;
      rstd = rsqrtf(var + 1e-5f);
    }
  }

  f32x4 acc[8];
  #pragma unroll
  for(int n = 0; n < 8; n++) acc[n] = f32x4{0.f,0.f,0.f,0.f};

  for(int kc = 0; kc < 16; kc++){
    int kd = kc*32 + g*8;
    const float* rp = xq + (row0 + li)*DIM + kd;
    f32x4 a0 = *(const f32x4*)rp;
    f32x4 a1 = *(const f32x4*)(rp + 4);
    f32x4 w0 = *(const f32x4*)(lnw + kd), w1 = *(const f32x4*)(lnw + kd + 4);
    f32x4 b0 = *(const f32x4*)(lnb + kd), b1 = *(const f32x4*)(lnb + kd + 4);
    s16x8 af;
    #pragma unroll
    for(int i = 0; i < 4; i++){
      af[i]   = f2bf((a0[i] - mean)*rstd*w0[i] + b0[i]);
      af[i+4] = f2bf((a1[i] - mean)*rstd*w1[i] + b1[i]);
    }
    #pragma unroll
    for(int n = 0; n < 8; n++){
      s16x8 bf = *(const s16x8*)(wqb + (n*16 + li)*DIM + kd);
      acc[n] = mfma16(af, bf, acc[n]);
    }
  }
  #pragma unroll
  for(int n = 0; n < 8; n++)
    #pragma unroll
    for(int r = 0; r < 4; r++){
      int m = row0 + g*4 + r;
      Q0[m*DH + n*16 + li] = acc[n][r];
    }
}

// ---------------- KV projection: 8 waves, K/V tile split across wave pairs (v11) ----------------
__global__ __launch_bounds__(512, 4) void k_kvproj(const float* __restrict__ xc,
                                                   const float* __restrict__ lnw, const float* __restrict__ lnb,
                                                   const short* __restrict__ wkvb, const float* __restrict__ rc,
                                                   const unsigned* __restrict__ bits,
                                                   const float* __restrict__ MU, const float* __restrict__ RS,
                                                   short* __restrict__ Kd, short* __restrict__ Vt){
  __shared__ __align__(16) short Klds[128][136];
  __shared__ __align__(16) short Vtlds[128][136];
  const int wid = threadIdx.x >> 6, lane = threadIdx.x & 63;
  const int g = lane >> 4, li = lane & 15;
  const int wk = wid & 3;          // row-group 0..3
  const int isV = wid >> 2;        // 0 = K tiles, 1 = V tiles
  const int b = blockIdx.y;
  const int s0 = blockIdx.x * 128;
  const int ws0 = s0 + wk * 32;

  float mean_s[2], rstd_s[2];
  #pragma unroll
  for(int sub = 0; sub < 2; sub++){
    size_t row = (size_t)b*SC + ws0 + sub*16 + li;
    mean_s[sub] = MU[row];
    rstd_s[sub] = RS[row];
  }

  f32x4 acc[8][2];
  #pragma unroll
  for(int n = 0; n < 8; n++){ acc[n][0] = f32x4{0.f,0.f,0.f,0.f}; acc[n][1] = f32x4{0.f,0.f,0.f,0.f}; }

  for(int kc = 0; kc < 8; kc++){
    int kd = kc*32 + g*8;
    f32x4 w0 = *(const f32x4*)(lnw + kd), w1 = *(const f32x4*)(lnw + kd + 4);
    f32x4 b0 = *(const f32x4*)(lnb + kd), b1 = *(const f32x4*)(lnb + kd + 4);
    s16x8 af[2];
    #pragma unroll
    for(int sub = 0; sub < 2; sub++){
      const float* rp = xc + ((size_t)b*SC + ws0 + sub*16 + li)*CDIM + kd;
      f32x4 a0 = *(const f32x4*)rp;
      f32x4 a1 = *(const f32x4*)(rp + 4);
      float mn = mean_s[sub], rs = rstd_s[sub];
      #pragma unroll
      for(int i = 0; i < 4; i++){
        af[sub][i]   = f2bf((a0[i]-mn)*rs*w0[i] + b0[i]);
        af[sub][i+4] = f2bf((a1[i]-mn)*rs*w1[i] + b1[i]);
      }
    }
    #pragma unroll
    for(int ntl = 0; ntl < 8; ntl++){
      const int nt = isV*8 + ntl;
      s16x8 bf = *(const s16x8*)(wkvb + (nt*16 + li)*CDIM + kd);
      acc[ntl][0] = mfma16(af[0], bf, acc[ntl][0]);
      acc[ntl][1] = mfma16(af[1], bf, acc[ntl][1]);
    }
  }

  // rotary + stage: K-waves -> Klds rows; V-waves -> Vtlds transposed
  if(isV == 0){
    #pragma unroll
    for(int ntl = 0; ntl < 8; ntl++)
      #pragma unroll
      for(int sub = 0; sub < 2; sub++)
        #pragma unroll
        for(int r = 0; r < 4; r++){
          int srow = wk*32 + sub*16 + g*4 + r;       // 0..127
          int d = ntl*16 + li;                       // 0..127
          float f = rc[((size_t)b*SC + s0 + srow)*DH + d];
          float sn, cs; __sincosf(f, &sn, &cs);
          float kv = acc[ntl][sub][r];
          float kp = __shfl_xor(kv, 1);
          float ky = (d & 1) ? (kv*cs + kp*sn) : (kv*cs - kp*sn);
          Klds[srow][d] = f2bf(ky);
        }
  } else {
    #pragma unroll
    for(int ntl = 0; ntl < 8; ntl++)
      #pragma unroll
      for(int sub = 0; sub < 2; sub++)
        #pragma unroll
        for(int r = 0; r < 4; r++){
          int srow = wk*32 + sub*16 + g*4 + r;
          int d = ntl*16 + li;
          float f = rc[((size_t)b*SC + s0 + srow)*DH + d];
          float sn, cs; __sincosf(f, &sn, &cs);
          float vv = acc[ntl][sub][r];
          float vp = __shfl_xor(vv, 1);
          float vy = (d & 1) ? (vv*cs + vp*sn) : (vv*cs - vp*sn);
          Vtlds[d][srow] = f2bf(vy);
        }
  }
  __syncthreads();
  for(int c = threadIdx.x; c < 2048; c += 512){
    int row = c >> 4, col = (c & 15) * 8;
    s16x8 kv = *(const s16x8*)&Klds[row][col];
    *(s16x8*)(Kd + ((size_t)b*SC + s0 + row)*DH + col) = kv;
    s16x8 vv = *(const s16x8*)&Vtlds[row][col];
    int sa = s0 + col;
    unsigned w = bits[b*64 + ((sa & 2047) >> 5)];
    unsigned mb = (w >> (sa & 31)) & 0xFFu;
    #pragma unroll
    for(int j = 0; j < 8; j++) if(!((mb >> j) & 1u)) vv[j] = 0;
    *(s16x8*)(Vt + (((size_t)b*128 + (sa >> 6))*VTR + row)*64 + (sa & 63)) = vv;
  }
}

// ---------------- attention ----------------
// grid 1024 = b(16) x qt(8) x kq(8); block = 8 waves x 16 q-rows (128-q tile);
// 32-key LDS steps (Kbuf 2x8KB + Vbuf 2x9KB = 34KB -> 4 blocks/CU,
// 8 waves/SIMD). 32 steps of 32 keys (1024 = one key-eighth). Single barrier
// per step; bf16 partial AOp out.
__global__ __launch_bounds__(512, 8) void k_attn(const float* __restrict__ Q0, const float* __restrict__ rq,
                                                 const short* __restrict__ Kd, const short* __restrict__ Vt,
                                                 short* __restrict__ AOp, float* __restrict__ ML){
  __shared__ __align__(16) short Kbuf[2][32*128];   // 2 x 8KB
  __shared__ __align__(16) short Vbuf[2][VTR*32];   // 2 x 9KB
  const int wid = threadIdx.x >> 6, lane = threadIdx.x & 63;
  const int g = lane >> 4, li = lane & 15;
  // XCD-grouped decode: 1024 blocks, 128 consecutive per XCD (= 2 batches)
  const int oid = (blockIdx.x & 7) * 128 + (blockIdx.x >> 3);
  const int b  = oid >> 6;
  const int rem = oid & 63;
  const int qt = rem >> 3;
  const int kq = rem & 7;
  const int qw0 = qt*128 + wid*16;     // wave owns 16 q rows
  constexpr float C2 = 0.08838834764831845f * 1.4426950408889634f; // scale * log2(e)

  // Q fragment (one 16-q group) with rotary applied, pre-scaled by C2, bf16
  s16x8 qf[4];
  {
    int qrow = qw0 + li;
    #pragma unroll
    for(int c = 0; c < 4; c++){
      int d0 = c*32 + g*8;
      const float* qp = Q0 + qrow*DH + d0;
      const float* fp = rq + ((size_t)b*NQ + qrow)*DH + d0;
      f32x4 x0 = *(const f32x4*)qp,     x1 = *(const f32x4*)(qp+4);
      f32x4 f0 = *(const f32x4*)fp,     f1 = *(const f32x4*)(fp+4);
      float xs[8] = {x0[0],x0[1],x0[2],x0[3],x1[0],x1[1],x1[2],x1[3]};
      float fs[8] = {f0[0],f0[1],f0[2],f0[3],f1[0],f1[1],f1[2],f1[3]};
      #pragma unroll
      for(int i = 0; i < 4; i++){
        float se, ce, so, co;
        __sincosf(fs[2*i],   &se, &ce);
        __sincosf(fs[2*i+1], &so, &co);
        qf[c][2*i]   = f2bf((xs[2*i]*ce   - xs[2*i+1]*se) * C2);
        qf[c][2*i+1] = f2bf((xs[2*i+1]*co + xs[2*i]*so) * C2);
      }
    }
  }

  float mrun = -1e30f;
  f32x4 acc[9];
  #pragma unroll
  for(int dt = 0; dt < 9; dt++) acc[dt] = f32x4{0.f,0.f,0.f,0.f};

  const char* Kg = (const char*)(Kd + ((size_t)b*SC + kq*1024)*DH);      // 256B rows
  const char* Vg = (const char*)(Vt + ((size_t)b*128 + kq*16)*VTILE);    // 16 64-key tiles

  const int ia0 = (((lane >> 4) & 1) * 32 + li) << 2;
  const int ia1 = ia0 + 64;
  const bool hi = (g >= 2);

  // staging per step (32 keys): K 8KB = 8 issues (1/wave, 4 rows each,
  // XOR-swizzled); V 144 rows x 64B = 9 issues (1/wave 16 rows, wave0 extra
  // for rows 128-143), linear.
  #define STAGE(bufi, t) do{                                                   \
    const char* Ksrc = Kg + (size_t)(t)*32*256;                                \
    {                                                                          \
      int rp = wid*4 + (lane >> 4);                                            \
      int bi = ((lane & 15)*16) ^ ((rp & 7) << 4);                             \
      gload16(Ksrc + rp*256 + bi, &Kbuf[bufi][(wid*4)*128]);                   \
    }                                                                          \
    const char* Vsrc = Vg + (size_t)((t) >> 1)*VTILE*2 + ((t) & 1)*64;         \
    {                                                                          \
      int rp = wid*16 + (lane >> 2);                                           \
      gload16(Vsrc + rp*128 + (lane & 3)*16, &Vbuf[bufi][(wid*16)*32]);        \
    }                                                                          \
    if(wid == 0){                                                              \
      int rp = 128 + (lane >> 2);                                              \
      gload16(Vsrc + rp*128 + (lane & 3)*16, &Vbuf[bufi][128*32]);             \
    }                                                                          \
  }while(0)

  STAGE(0, 0);
  __syncthreads();                     // prologue: buf0 staged & visible

  for(int t = 0; t < 32; ++t){
    const int cur = t & 1;
    if(t < 31) STAGE(cur^1, t+1);      // loads stay in flight during compute

    // QK: St[k, q] for 32 keys
    f32x4 st[2];
    __builtin_amdgcn_s_setprio(1);
    #pragma unroll
    for(int ks = 0; ks < 2; ks++){
      s16x8 kf[4];
      #pragma unroll
      for(int c = 0; c < 4; c++){
        int row = ks*16 + li;
        int off = row*256 + ((c*64 + g*16) ^ ((row & 7) << 4));
        kf[c] = *(const s16x8*)((const char*)&Kbuf[cur][0] + off);
      }
      f32x4 s = f32x4{0.f,0.f,0.f,0.f};
      #pragma unroll
      for(int c = 0; c < 4; c++) s = mfma16(kf[c], qf[c], s);
      st[ks] = s;
    }
    __builtin_amdgcn_s_setprio(0);

    // softmax + P B-frag
    s16x8 pf;
    {
      float mt = -1e30f;
      #pragma unroll
      for(int ks = 0; ks < 2; ks++)
        #pragma unroll
        for(int r = 0; r < 4; r++) mt = fmaxf(mt, st[ks][r]);
      mt = fmaxf(mt, __shfl_xor(mt, 16));
      mt = fmaxf(mt, __shfl_xor(mt, 32));
      if(__any(mt > mrun + 3.0f)){          // defer-rescale
        float mnew = fmaxf(mrun, mt);
        float a = exp2f(mrun - mnew);
        mrun = mnew;
        #pragma unroll
        for(int dt = 0; dt < 9; dt++) acc[dt] = acc[dt] * a;
      }
      float m = mrun;
      unsigned L0 = pk2(exp2f(st[0][0] - m), exp2f(st[0][1] - m));
      unsigned H0 = pk2(exp2f(st[0][2] - m), exp2f(st[0][3] - m));
      unsigned L1 = pk2(exp2f(st[1][0] - m), exp2f(st[1][1] - m));
      unsigned H1 = pk2(exp2f(st[1][2] - m), exp2f(st[1][3] - m));
      pf = pexch(ia0, ia1, hi, L0, H0, L1, H1);
    }

    // PV: acc^T[d, q] += V^T-tile x P  (K=32 per step)
    __builtin_amdgcn_s_setprio(1);
    #pragma unroll
    for(int dt = 0; dt < 9; dt++){
      int row = dt*16 + li;
      s16x8 vf = *(const s16x8*)&Vbuf[cur][row*32 + g*8];
      acc[dt] = mfma16(vf, pf, acc[dt]);
    }
    __builtin_amdgcn_s_setprio(0);

    __syncthreads();   // drains the t+1 loads (they flew during compute);
                       // also: all reads of cur done before t+2 re-stages it
  }

  // epilogue: each wave writes its own 16 q rows (bf16 partial O; f32 m, l)
  const size_t pbase = ((size_t)kq*NB + b)*NQ;
  if(lane < 16){
    size_t o = pbase + qw0 + li;
    ML[o*2]   = mrun;
    ML[o*2+1] = acc[8][0];
  }
  {
    size_t o = (pbase + qw0 + li)*DH;
    #pragma unroll
    for(int dt = 0; dt < 8; dt++){
      uint2 pk;
      pk.x = pk2(acc[dt][0], acc[dt][1]);
      pk.y = pk2(acc[dt][2], acc[dt][3]);
      *(uint2*)(AOp + o + dt*16 + g*4) = pk;
    }
  }
}

// ---------------- final part 1: merge 8 key-eighths + inverse rotary + partial mean ----------------
// grid (64,16): 16 queries per chunk.
__global__ __launch_bounds__(256) void k_fin1(const short* __restrict__ AOp, const float* __restrict__ ML,
                                              const float* __restrict__ rq, float* __restrict__ part){
  __shared__ float red[2][128];
  const int b = blockIdx.y, ch = blockIdx.x;
  const int t = threadIdx.x;
  const int d = t & 127, h = t >> 7;
  float acc = 0.f;
  #pragma unroll 2
  for(int i = 0; i < 8; i++){
    int n = ch*16 + h*8 + i;
    size_t qi = (size_t)b*NQ + n;
    float m[NKQ], l[NKQ];
    #pragma unroll
    for(int kq = 0; kq < NKQ; kq++){
      size_t o = (size_t)kq*NB*NQ + qi;
      m[kq] = ML[o*2]; l[kq] = ML[o*2+1];
    }
    float M = m[0];
    #pragma unroll
    for(int kq = 1; kq < NKQ; kq++) M = fmaxf(M, m[kq]);
    float w[NKQ], L = 0.f;
    #pragma unroll
    for(int kq = 0; kq < NKQ; kq++){ w[kq] = exp2f(m[kq] - M); L += w[kq]*l[kq]; }
    float inv = 1.f / L;
    float O = 0.f;
    #pragma unroll
    for(int kq = 0; kq < NKQ; kq++) O += w[kq]*bf2f(AOp[((size_t)kq*NB*NQ + qi)*DH + d]);
    O *= inv;
    float P = __shfl_xor(O, 1);
    float f = rq[qi*DH + d];
    float sn, cs; __sincosf(f, &sn, &cs);
    acc += (d & 1) ? (O*cs - P*sn) : (O*cs + P*sn);   // rotary with -f
  }
  red[h][d] = acc;
  __syncthreads();
  if(h == 0) part[((size_t)b*64 + ch)*128 + d] = red[0][d] + red[1][d];
}

// ---------------- final part 2: reduce chunks + @ w_o^T + b_o ----------------
__global__ __launch_bounds__(256) void k_fin2(const float* __restrict__ part,
                                              const float* __restrict__ wo, const float* __restrict__ bo,
                                              float* __restrict__ out){
  __shared__ float sm[128];
  const int b = blockIdx.x, t = threadIdx.x;
  if(t < 128){
    float s = 0.f;
    for(int ch = 0; ch < 64; ch++) s += part[((size_t)b*64 + ch)*128 + t];
    sm[t] = s * (1.0f / NQ);
  }
  __syncthreads();
  for(int o = t; o < DIM; o += 256){
    float s = bo[o];
    const float* wr = wo + o*DH;
    #pragma unroll 4
    for(int j = 0; j < DH; j++) s += sm[j] * wr[j];
    out[b*DIM + o] = s;
  }
}

extern "C" void kernel_launch(void* const* d_in, const int* in_sizes, int n_in,
                              void* d_out, int out_size, void* d_ws, size_t ws_size,
                              hipStream_t stream){
  const float* xq   = (const float*)d_in[0];
  const float* xc   = (const float*)d_in[1];
  const float* rq   = (const float*)d_in[2];
  const float* rc   = (const float*)d_in[3];
  const unsigned char* mask = (const unsigned char*)d_in[4];
  const float* lnqw = (const float*)d_in[5];
  const float* lnqb = (const float*)d_in[6];
  const float* lncw = (const float*)d_in[7];
  const float* lncb = (const float*)d_in[8];
  const float* wq   = (const float*)d_in[9];
  const float* wkv  = (const float*)d_in[10];
  const float* wo   = (const float*)d_in[11];
  const float* bo   = (const float*)d_in[12];
  float* out = (float*)d_out;

  char* ws = (char*)d_ws;
  size_t off = 0;
  auto alloc = [&](size_t bytes){ void* p = ws + off; off += (bytes + 255) & ~(size_t)255; return p; };
  float*    Q0   = (float*)   alloc((size_t)NQ*DH*4);
  short*    wqb  = (short*)   alloc((size_t)128*512*2);
  short*    wkvb = (short*)   alloc((size_t)256*256*2);
  unsigned* bits = (unsigned*)alloc((size_t)NB*64*4);
  float*    MU   = (float*)   alloc((size_t)NB*SC*4);             // 0.5MB
  float*    RS   = (float*)   alloc((size_t)NB*SC*4);             // 0.5MB
  short*    Kd   = (short*)   alloc((size_t)NB*SC*DH*2);          // 32MB
  short*    Vt   = (short*)   alloc((size_t)NB*128*VTILE*2);      // 37.7MB tiled
  short*    AOp  = (short*)   alloc((size_t)NKQ*NB*NQ*DH*2);      // 33.5MB bf16
  float*    ML   = (float*)   alloc((size_t)NKQ*NB*NQ*2*4);       // 1MB
  float*    part = (float*)   alloc((size_t)NB*64*128*4);

  k_cvtw  <<<dim3(256),     dim3(256), 0, stream>>>(wq, wkv, wqb, wkvb);
  k_mask  <<<dim3(16),      dim3(256), 0, stream>>>(mask, bits);
  k_vrow  <<<dim3(32,16),   dim3(256), 0, stream>>>(bits, Vt);
  k_stats <<<dim3(NB*SC/16),dim3(256), 0, stream>>>(xc, MU, RS);
  k_qproj <<<dim3(16),      dim3(256), 0, stream>>>(xq, lnqw, lnqb, wqb, Q0);
  k_kvproj<<<dim3(64,16),   dim3(512), 0, stream>>>(xc, lncw, lncb, wkvb, rc, bits, MU, RS, Kd, Vt);
  k_attn  <<<dim3(1024),    dim3(512), 0, stream>>>(Q0, rq, Kd, Vt, AOp, ML);
  k_fin1  <<<dim3(64,16),   dim3(256), 0, stream>>>(AOp, ML, rq, part);
  k_fin2  <<<dim3(16),      dim3(256), 0, stream>>>(part, wo, bo, out);
}

// Round 16
// 373.831 us; speedup vs baseline: 1.7097x; 1.7097x over previous
//
#include <hip/hip_runtime.h>
#include <hip/hip_bf16.h>

// RotaryCrossAttention on MI355X (gfx950).
// v16 = v15 with ONE change: k_attn __launch_bounds__(512,8) -> (512,4).
//      (512,8) forced VGPR=32 (natural ~80) -> catastrophic spill (FETCH
//      1.1GB scratch, 400us) — same failure as R12's kvproj. (512,4) caps at
//      128: no spills, ~3 blocks/CU (6 waves/SIMD) via LDS 34KB + VGPR ~80.
// Pipeline: k_cvtw ; k_mask ; k_vrow ; k_stats ; k_qproj ; k_kvproj ;
//           k_attn ; k_fin1 ; k_fin2

#define DEV static __device__ __forceinline__

typedef __attribute__((ext_vector_type(4))) float f32x4;
typedef __attribute__((ext_vector_type(8))) short s16x8;
typedef __attribute__((ext_vector_type(4))) unsigned u32x4;

constexpr int NB   = 16;
constexpr int NQ   = 1024;
constexpr int SC   = 8192;   // T*C
constexpr int DIM  = 512;
constexpr int CDIM = 256;
constexpr int DH   = 128;
constexpr int VTR  = 144;    // V tile rows: d 0..127, row128 = mask-ones, 129..143 dead
constexpr int VTILE = VTR*64; // elems per 64-key V tile (18KB)
constexpr int NKQ  = 8;      // key splits

DEV short f2bf(float x){
  unsigned u = __builtin_bit_cast(unsigned, x);
  unsigned r = (u + 0x7FFFu + ((u >> 16) & 1u)) >> 16;
  return (short)r;
}

DEV float bf2f(short v){
  unsigned u = ((unsigned)(unsigned short)v) << 16;
  return __builtin_bit_cast(float, u);
}

DEV unsigned pk2(float a, float b){
  unsigned short ua = __builtin_bit_cast(unsigned short, __float2bfloat16(a));
  unsigned short ub = __builtin_bit_cast(unsigned short, __float2bfloat16(b));
  return (unsigned)ua | ((unsigned)ub << 16);
}

DEV f32x4 mfma16(s16x8 a, s16x8 b, f32x4 c){
  return __builtin_amdgcn_mfma_f32_16x16x32_bf16(a, b, c, 0, 0, 0);
}

DEV void gload16(const void* g, void* l){
  __builtin_amdgcn_global_load_lds(
      (const __attribute__((address_space(1))) void*)g,
      (__attribute__((address_space(3))) void*)l, 16, 0, 0);
}

// P cross-lane exchange (verified v3): C-layout St rows -> PV B-frag.
DEV s16x8 pexch(int ia0, int ia1, bool hi, unsigned L0, unsigned H0, unsigned L1, unsigned H1){
  int aL0 = __builtin_amdgcn_ds_bpermute(ia0, (int)L0);
  int aL1 = __builtin_amdgcn_ds_bpermute(ia0, (int)L1);
  int aH0 = __builtin_amdgcn_ds_bpermute(ia0, (int)H0);
  int aH1 = __builtin_amdgcn_ds_bpermute(ia0, (int)H1);
  int bL0 = __builtin_amdgcn_ds_bpermute(ia1, (int)L0);
  int bL1 = __builtin_amdgcn_ds_bpermute(ia1, (int)L1);
  int bH0 = __builtin_amdgcn_ds_bpermute(ia1, (int)H0);
  int bH1 = __builtin_amdgcn_ds_bpermute(ia1, (int)H1);
  u32x4 r;
  r[0] = (unsigned)(hi ? aL1 : aL0);
  r[1] = (unsigned)(hi ? aH1 : aH0);
  r[2] = (unsigned)(hi ? bL1 : bL0);
  r[3] = (unsigned)(hi ? bH1 : bH0);
  return __builtin_bit_cast(s16x8, r);
}

// ---------------- weights f32 -> bf16 ----------------
__global__ void k_cvtw(const float* __restrict__ wq, const float* __restrict__ wkv,
                       short* __restrict__ wqb, short* __restrict__ wkvb){
  int i = blockIdx.x * 256 + threadIdx.x;
  if(i < 128*512) wqb[i]  = f2bf(wq[i]);
  if(i < 256*256) wkvb[i] = f2bf(wkv[i]);
}

// ---------------- mask: detect bool(1B) vs int32(4B), pack to bits ----------------
__global__ void k_mask(const unsigned char* __restrict__ raw, unsigned* __restrict__ bits){
  const int b = blockIdx.x, t = threadIdx.x;
  int nz = 0;
  for(int i = t; i < 8192; i += 256){       // first 32KB valid under both layouts
    unsigned w = ((const unsigned*)raw)[i];
    if(w & 0xFFFFFF00u) nz = 1;
  }
  int any = __syncthreads_or(nz);
  bool isInt = (any == 0);
  if(t < 64){
    unsigned out = 0;
    if(isInt){
      const int* p = (const int*)raw + (b*2048 + t*32);
      for(int j = 0; j < 32; j++) out |= (unsigned)(p[j] != 0) << j;
    } else {
      const unsigned char* p = raw + (b*2048 + t*32);
      for(int j = 0; j < 32; j++) out |= (unsigned)(p[j] != 0) << j;
    }
    bits[b*64 + t] = out;
  }
}

// ---------------- V tile row 128 = mask as bf16 ones ----------------
__global__ void k_vrow(const unsigned* __restrict__ bits, short* __restrict__ Vt){
  int b = blockIdx.y;
  int s = blockIdx.x * 256 + threadIdx.x;    // 0..8191
  unsigned w = bits[b*64 + ((s & 2047) >> 5)];
  short v = ((w >> (s & 31)) & 1u) ? (short)0x3F80 : (short)0;
  Vt[(((size_t)b*128 + (s >> 6))*VTR + 128)*64 + (s & 63)] = v;
}

// ---------------- LN stats for context rows: mu/rstd per row ----------------
__global__ __launch_bounds__(256) void k_stats(const float* __restrict__ xc,
                                               float* __restrict__ MU, float* __restrict__ RS){
  const size_t row = (size_t)blockIdx.x * 16 + (threadIdx.x >> 4);   // global row in [0, NB*SC)
  const int cl = (threadIdx.x & 15) * 16;
  const float* rp = xc + row * CDIM + cl;
  float s = 0.f, sq = 0.f;
  #pragma unroll
  for(int i = 0; i < 4; i++){
    f32x4 a = *(const f32x4*)(rp + i*4);
    #pragma unroll
    for(int j = 0; j < 4; j++){ s += a[j]; sq += a[j]*a[j]; }
  }
  #pragma unroll
  for(int o = 8; o > 0; o >>= 1){ s += __shfl_xor(s, o); sq += __shfl_xor(sq, o); }
  if((threadIdx.x & 15) == 0){
    float m = s * (1.f/CDIM);
    MU[row] = m;
    RS[row] = rsqrtf(sq * (1.f/CDIM) - m*m + 1e-5f);
  }
}

// ---------------- Q projection: LN + GEMM (1024x512 @ 512x128) ----------------
__global__ __launch_bounds__(256) void k_qproj(const float* __restrict__ xq,
                                               const float* __restrict__ lnw, const float* __restrict__ lnb,
                                               const short* __restrict__ wqb, float* __restrict__ Q0){
  const int wid = threadIdx.x >> 6, lane = threadIdx.x & 63;
  const int g = lane >> 4, li = lane & 15;
  const int row0 = blockIdx.x * 64 + wid * 16;

  float mean = 0.f, rstd = 0.f;
  #pragma unroll
  for(int r = 0; r < 16; r++){
    const float* rp = xq + (row0 + r) * DIM;
    f32x4 a = *(const f32x4*)(rp + lane*8);
    f32x4 b = *(const f32x4*)(rp + lane*8 + 4);
    float s = 0.f, sq = 0.f;
    #pragma unroll
    for(int i = 0; i < 4; i++){ s += a[i] + b[i]; sq += a[i]*a[i] + b[i]*b[i]; }
    #pragma unroll
    for(int o = 32; o > 0; o >>= 1){ s += __shfl_xor(s, o); sq += __shfl_xor(sq, o); }
    if(li == r){
      mean = s / DIM;
      float var = sq / DIM - mean*mean;
      rstd = rsqrtf(var + 1e-5f);
    }
  }

  f32x4 acc[8];
  #pragma unroll
  for(int n = 0; n < 8; n++) acc[n] = f32x4{0.f,0.f,0.f,0.f};

  for(int kc = 0; kc < 16; kc++){
    int kd = kc*32 + g*8;
    const float* rp = xq + (row0 + li)*DIM + kd;
    f32x4 a0 = *(const f32x4*)rp;
    f32x4 a1 = *(const f32x4*)(rp + 4);
    f32x4 w0 = *(const f32x4*)(lnw + kd), w1 = *(const f32x4*)(lnw + kd + 4);
    f32x4 b0 = *(const f32x4*)(lnb + kd), b1 = *(const f32x4*)(lnb + kd + 4);
    s16x8 af;
    #pragma unroll
    for(int i = 0; i < 4; i++){
      af[i]   = f2bf((a0[i] - mean)*rstd*w0[i] + b0[i]);
      af[i+4] = f2bf((a1[i] - mean)*rstd*w1[i] + b1[i]);
    }
    #pragma unroll
    for(int n = 0; n < 8; n++){
      s16x8 bf = *(const s16x8*)(wqb + (n*16 + li)*DIM + kd);
      acc[n] = mfma16(af, bf, acc[n]);
    }
  }
  #pragma unroll
  for(int n = 0; n < 8; n++)
    #pragma unroll
    for(int r = 0; r < 4; r++){
      int m = row0 + g*4 + r;
      Q0[m*DH + n*16 + li] = acc[n][r];
    }
}

// ---------------- KV projection: 8 waves, K/V tile split across wave pairs (v11) ----------------
__global__ __launch_bounds__(512, 4) void k_kvproj(const float* __restrict__ xc,
                                                   const float* __restrict__ lnw, const float* __restrict__ lnb,
                                                   const short* __restrict__ wkvb, const float* __restrict__ rc,
                                                   const unsigned* __restrict__ bits,
                                                   const float* __restrict__ MU, const float* __restrict__ RS,
                                                   short* __restrict__ Kd, short* __restrict__ Vt){
  __shared__ __align__(16) short Klds[128][136];
  __shared__ __align__(16) short Vtlds[128][136];
  const int wid = threadIdx.x >> 6, lane = threadIdx.x & 63;
  const int g = lane >> 4, li = lane & 15;
  const int wk = wid & 3;          // row-group 0..3
  const int isV = wid >> 2;        // 0 = K tiles, 1 = V tiles
  const int b = blockIdx.y;
  const int s0 = blockIdx.x * 128;
  const int ws0 = s0 + wk * 32;

  float mean_s[2], rstd_s[2];
  #pragma unroll
  for(int sub = 0; sub < 2; sub++){
    size_t row = (size_t)b*SC + ws0 + sub*16 + li;
    mean_s[sub] = MU[row];
    rstd_s[sub] = RS[row];
  }

  f32x4 acc[8][2];
  #pragma unroll
  for(int n = 0; n < 8; n++){ acc[n][0] = f32x4{0.f,0.f,0.f,0.f}; acc[n][1] = f32x4{0.f,0.f,0.f,0.f}; }

  for(int kc = 0; kc < 8; kc++){
    int kd = kc*32 + g*8;
    f32x4 w0 = *(const f32x4*)(lnw + kd), w1 = *(const f32x4*)(lnw + kd + 4);
    f32x4 b0 = *(const f32x4*)(lnb + kd), b1 = *(const f32x4*)(lnb + kd + 4);
    s16x8 af[2];
    #pragma unroll
    for(int sub = 0; sub < 2; sub++){
      const float* rp = xc + ((size_t)b*SC + ws0 + sub*16 + li)*CDIM + kd;
      f32x4 a0 = *(const f32x4*)rp;
      f32x4 a1 = *(const f32x4*)(rp + 4);
      float mn = mean_s[sub], rs = rstd_s[sub];
      #pragma unroll
      for(int i = 0; i < 4; i++){
        af[sub][i]   = f2bf((a0[i]-mn)*rs*w0[i] + b0[i]);
        af[sub][i+4] = f2bf((a1[i]-mn)*rs*w1[i] + b1[i]);
      }
    }
    #pragma unroll
    for(int ntl = 0; ntl < 8; ntl++){
      const int nt = isV*8 + ntl;
      s16x8 bf = *(const s16x8*)(wkvb + (nt*16 + li)*CDIM + kd);
      acc[ntl][0] = mfma16(af[0], bf, acc[ntl][0]);
      acc[ntl][1] = mfma16(af[1], bf, acc[ntl][1]);
    }
  }

  // rotary + stage: K-waves -> Klds rows; V-waves -> Vtlds transposed
  if(isV == 0){
    #pragma unroll
    for(int ntl = 0; ntl < 8; ntl++)
      #pragma unroll
      for(int sub = 0; sub < 2; sub++)
        #pragma unroll
        for(int r = 0; r < 4; r++){
          int srow = wk*32 + sub*16 + g*4 + r;       // 0..127
          int d = ntl*16 + li;                       // 0..127
          float f = rc[((size_t)b*SC + s0 + srow)*DH + d];
          float sn, cs; __sincosf(f, &sn, &cs);
          float kv = acc[ntl][sub][r];
          float kp = __shfl_xor(kv, 1);
          float ky = (d & 1) ? (kv*cs + kp*sn) : (kv*cs - kp*sn);
          Klds[srow][d] = f2bf(ky);
        }
  } else {
    #pragma unroll
    for(int ntl = 0; ntl < 8; ntl++)
      #pragma unroll
      for(int sub = 0; sub < 2; sub++)
        #pragma unroll
        for(int r = 0; r < 4; r++){
          int srow = wk*32 + sub*16 + g*4 + r;
          int d = ntl*16 + li;
          float f = rc[((size_t)b*SC + s0 + srow)*DH + d];
          float sn, cs; __sincosf(f, &sn, &cs);
          float vv = acc[ntl][sub][r];
          float vp = __shfl_xor(vv, 1);
          float vy = (d & 1) ? (vv*cs + vp*sn) : (vv*cs - vp*sn);
          Vtlds[d][srow] = f2bf(vy);
        }
  }
  __syncthreads();
  for(int c = threadIdx.x; c < 2048; c += 512){
    int row = c >> 4, col = (c & 15) * 8;
    s16x8 kv = *(const s16x8*)&Klds[row][col];
    *(s16x8*)(Kd + ((size_t)b*SC + s0 + row)*DH + col) = kv;
    s16x8 vv = *(const s16x8*)&Vtlds[row][col];
    int sa = s0 + col;
    unsigned w = bits[b*64 + ((sa & 2047) >> 5)];
    unsigned mb = (w >> (sa & 31)) & 0xFFu;
    #pragma unroll
    for(int j = 0; j < 8; j++) if(!((mb >> j) & 1u)) vv[j] = 0;
    *(s16x8*)(Vt + (((size_t)b*128 + (sa >> 6))*VTR + row)*64 + (sa & 63)) = vv;
  }
}

// ---------------- attention ----------------
// grid 1024 = b(16) x qt(8) x kq(8); block = 8 waves x 16 q-rows (128-q tile);
// 32-key LDS steps (Kbuf 2x8KB + Vbuf 2x9KB = 34KB). Single barrier per step;
// bf16 partial AOp out. launch_bounds (512,4): natural VGPR ~80, no spill.
__global__ __launch_bounds__(512, 4) void k_attn(const float* __restrict__ Q0, const float* __restrict__ rq,
                                                 const short* __restrict__ Kd, const short* __restrict__ Vt,
                                                 short* __restrict__ AOp, float* __restrict__ ML){
  __shared__ __align__(16) short Kbuf[2][32*128];   // 2 x 8KB
  __shared__ __align__(16) short Vbuf[2][VTR*32];   // 2 x 9KB
  const int wid = threadIdx.x >> 6, lane = threadIdx.x & 63;
  const int g = lane >> 4, li = lane & 15;
  // XCD-grouped decode: 1024 blocks, 128 consecutive per XCD (= 2 batches)
  const int oid = (blockIdx.x & 7) * 128 + (blockIdx.x >> 3);
  const int b  = oid >> 6;
  const int rem = oid & 63;
  const int qt = rem >> 3;
  const int kq = rem & 7;
  const int qw0 = qt*128 + wid*16;     // wave owns 16 q rows
  constexpr float C2 = 0.08838834764831845f * 1.4426950408889634f; // scale * log2(e)

  // Q fragment (one 16-q group) with rotary applied, pre-scaled by C2, bf16
  s16x8 qf[4];
  {
    int qrow = qw0 + li;
    #pragma unroll
    for(int c = 0; c < 4; c++){
      int d0 = c*32 + g*8;
      const float* qp = Q0 + qrow*DH + d0;
      const float* fp = rq + ((size_t)b*NQ + qrow)*DH + d0;
      f32x4 x0 = *(const f32x4*)qp,     x1 = *(const f32x4*)(qp+4);
      f32x4 f0 = *(const f32x4*)fp,     f1 = *(const f32x4*)(fp+4);
      float xs[8] = {x0[0],x0[1],x0[2],x0[3],x1[0],x1[1],x1[2],x1[3]};
      float fs[8] = {f0[0],f0[1],f0[2],f0[3],f1[0],f1[1],f1[2],f1[3]};
      #pragma unroll
      for(int i = 0; i < 4; i++){
        float se, ce, so, co;
        __sincosf(fs[2*i],   &se, &ce);
        __sincosf(fs[2*i+1], &so, &co);
        qf[c][2*i]   = f2bf((xs[2*i]*ce   - xs[2*i+1]*se) * C2);
        qf[c][2*i+1] = f2bf((xs[2*i+1]*co + xs[2*i]*so) * C2);
      }
    }
  }

  float mrun = -1e30f;
  f32x4 acc[9];
  #pragma unroll
  for(int dt = 0; dt < 9; dt++) acc[dt] = f32x4{0.f,0.f,0.f,0.f};

  const char* Kg = (const char*)(Kd + ((size_t)b*SC + kq*1024)*DH);      // 256B rows
  const char* Vg = (const char*)(Vt + ((size_t)b*128 + kq*16)*VTILE);    // 16 64-key tiles

  const int ia0 = (((lane >> 4) & 1) * 32 + li) << 2;
  const int ia1 = ia0 + 64;
  const bool hi = (g >= 2);

  // staging per step (32 keys): K 8KB = 8 issues (1/wave, 4 rows each,
  // XOR-swizzled); V 144 rows x 64B = 9 issues (1/wave 16 rows, wave0 extra
  // for rows 128-143), linear.
  #define STAGE(bufi, t) do{                                                   \
    const char* Ksrc = Kg + (size_t)(t)*32*256;                                \
    {                                                                          \
      int rp = wid*4 + (lane >> 4);                                            \
      int bi = ((lane & 15)*16) ^ ((rp & 7) << 4);                             \
      gload16(Ksrc + rp*256 + bi, &Kbuf[bufi][(wid*4)*128]);                   \
    }                                                                          \
    const char* Vsrc = Vg + (size_t)((t) >> 1)*VTILE*2 + ((t) & 1)*64;         \
    {                                                                          \
      int rp = wid*16 + (lane >> 2);                                           \
      gload16(Vsrc + rp*128 + (lane & 3)*16, &Vbuf[bufi][(wid*16)*32]);        \
    }                                                                          \
    if(wid == 0){                                                              \
      int rp = 128 + (lane >> 2);                                              \
      gload16(Vsrc + rp*128 + (lane & 3)*16, &Vbuf[bufi][128*32]);             \
    }                                                                          \
  }while(0)

  STAGE(0, 0);
  __syncthreads();                     // prologue: buf0 staged & visible

  for(int t = 0; t < 32; ++t){
    const int cur = t & 1;
    if(t < 31) STAGE(cur^1, t+1);      // loads stay in flight during compute

    // QK: St[k, q] for 32 keys
    f32x4 st[2];
    __builtin_amdgcn_s_setprio(1);
    #pragma unroll
    for(int ks = 0; ks < 2; ks++){
      s16x8 kf[4];
      #pragma unroll
      for(int c = 0; c < 4; c++){
        int row = ks*16 + li;
        int off = row*256 + ((c*64 + g*16) ^ ((row & 7) << 4));
        kf[c] = *(const s16x8*)((const char*)&Kbuf[cur][0] + off);
      }
      f32x4 s = f32x4{0.f,0.f,0.f,0.f};
      #pragma unroll
      for(int c = 0; c < 4; c++) s = mfma16(kf[c], qf[c], s);
      st[ks] = s;
    }
    __builtin_amdgcn_s_setprio(0);

    // softmax + P B-frag
    s16x8 pf;
    {
      float mt = -1e30f;
      #pragma unroll
      for(int ks = 0; ks < 2; ks++)
        #pragma unroll
        for(int r = 0; r < 4; r++) mt = fmaxf(mt, st[ks][r]);
      mt = fmaxf(mt, __shfl_xor(mt, 16));
      mt = fmaxf(mt, __shfl_xor(mt, 32));
      if(__any(mt > mrun + 3.0f)){          // defer-rescale
        float mnew = fmaxf(mrun, mt);
        float a = exp2f(mrun - mnew);
        mrun = mnew;
        #pragma unroll
        for(int dt = 0; dt < 9; dt++) acc[dt] = acc[dt] * a;
      }
      float m = mrun;
      unsigned L0 = pk2(exp2f(st[0][0] - m), exp2f(st[0][1] - m));
      unsigned H0 = pk2(exp2f(st[0][2] - m), exp2f(st[0][3] - m));
      unsigned L1 = pk2(exp2f(st[1][0] - m), exp2f(st[1][1] - m));
      unsigned H1 = pk2(exp2f(st[1][2] - m), exp2f(st[1][3] - m));
      pf = pexch(ia0, ia1, hi, L0, H0, L1, H1);
    }

    // PV: acc^T[d, q] += V^T-tile x P  (K=32 per step)
    __builtin_amdgcn_s_setprio(1);
    #pragma unroll
    for(int dt = 0; dt < 9; dt++){
      int row = dt*16 + li;
      s16x8 vf = *(const s16x8*)&Vbuf[cur][row*32 + g*8];
      acc[dt] = mfma16(vf, pf, acc[dt]);
    }
    __builtin_amdgcn_s_setprio(0);

    __syncthreads();   // drains the t+1 loads (they flew during compute);
                       // also: all reads of cur done before t+2 re-stages it
  }

  // epilogue: each wave writes its own 16 q rows (bf16 partial O; f32 m, l)
  const size_t pbase = ((size_t)kq*NB + b)*NQ;
  if(lane < 16){
    size_t o = pbase + qw0 + li;
    ML[o*2]   = mrun;
    ML[o*2+1] = acc[8][0];
  }
  {
    size_t o = (pbase + qw0 + li)*DH;
    #pragma unroll
    for(int dt = 0; dt < 8; dt++){
      uint2 pk;
      pk.x = pk2(acc[dt][0], acc[dt][1]);
      pk.y = pk2(acc[dt][2], acc[dt][3]);
      *(uint2*)(AOp + o + dt*16 + g*4) = pk;
    }
  }
}

// ---------------- final part 1: merge 8 key-eighths + inverse rotary + partial mean ----------------
// grid (64,16): 16 queries per chunk.
__global__ __launch_bounds__(256) void k_fin1(const short* __restrict__ AOp, const float* __restrict__ ML,
                                              const float* __restrict__ rq, float* __restrict__ part){
  __shared__ float red[2][128];
  const int b = blockIdx.y, ch = blockIdx.x;
  const int t = threadIdx.x;
  const int d = t & 127, h = t >> 7;
  float acc = 0.f;
  #pragma unroll 2
  for(int i = 0; i < 8; i++){
    int n = ch*16 + h*8 + i;
    size_t qi = (size_t)b*NQ + n;
    float m[NKQ], l[NKQ];
    #pragma unroll
    for(int kq = 0; kq < NKQ; kq++){
      size_t o = (size_t)kq*NB*NQ + qi;
      m[kq] = ML[o*2]; l[kq] = ML[o*2+1];
    }
    float M = m[0];
    #pragma unroll
    for(int kq = 1; kq < NKQ; kq++) M = fmaxf(M, m[kq]);
    float w[NKQ], L = 0.f;
    #pragma unroll
    for(int kq = 0; kq < NKQ; kq++){ w[kq] = exp2f(m[kq] - M); L += w[kq]*l[kq]; }
    float inv = 1.f / L;
    float O = 0.f;
    #pragma unroll
    for(int kq = 0; kq < NKQ; kq++) O += w[kq]*bf2f(AOp[((size_t)kq*NB*NQ + qi)*DH + d]);
    O *= inv;
    float P = __shfl_xor(O, 1);
    float f = rq[qi*DH + d];
    float sn, cs; __sincosf(f, &sn, &cs);
    acc += (d & 1) ? (O*cs - P*sn) : (O*cs + P*sn);   // rotary with -f
  }
  red[h][d] = acc;
  __syncthreads();
  if(h == 0) part[((size_t)b*64 + ch)*128 + d] = red[0][d] + red[1][d];
}

// ---------------- final part 2: reduce chunks + @ w_o^T + b_o ----------------
__global__ __launch_bounds__(256) void k_fin2(const float* __restrict__ part,
                                              const float* __restrict__ wo, const float* __restrict__ bo,
                                              float* __restrict__ out){
  __shared__ float sm[128];
  const int b = blockIdx.x, t = threadIdx.x;
  if(t < 128){
    float s = 0.f;
    for(int ch = 0; ch < 64; ch++) s += part[((size_t)b*64 + ch)*128 + t];
    sm[t] = s * (1.0f / NQ);
  }
  __syncthreads();
  for(int o = t; o < DIM; o += 256){
    float s = bo[o];
    const float* wr = wo + o*DH;
    #pragma unroll 4
    for(int j = 0; j < DH; j++) s += sm[j] * wr[j];
    out[b*DIM + o] = s;
  }
}

extern "C" void kernel_launch(void* const* d_in, const int* in_sizes, int n_in,
                              void* d_out, int out_size, void* d_ws, size_t ws_size,
                              hipStream_t stream){
  const float* xq   = (const float*)d_in[0];
  const float* xc   = (const float*)d_in[1];
  const float* rq   = (const float*)d_in[2];
  const float* rc   = (const float*)d_in[3];
  const unsigned char* mask = (const unsigned char*)d_in[4];
  const float* lnqw = (const float*)d_in[5];
  const float* lnqb = (const float*)d_in[6];
  const float* lncw = (const float*)d_in[7];
  const float* lncb = (const float*)d_in[8];
  const float* wq   = (const float*)d_in[9];
  const float* wkv  = (const float*)d_in[10];
  const float* wo   = (const float*)d_in[11];
  const float* bo   = (const float*)d_in[12];
  float* out = (float*)d_out;

  char* ws = (char*)d_ws;
  size_t off = 0;
  auto alloc = [&](size_t bytes){ void* p = ws + off; off += (bytes + 255) & ~(size_t)255; return p; };
  float*    Q0   = (float*)   alloc((size_t)NQ*DH*4);
  short*    wqb  = (short*)   alloc((size_t)128*512*2);
  short*    wkvb = (short*)   alloc((size_t)256*256*2);
  unsigned* bits = (unsigned*)alloc((size_t)NB*64*4);
  float*    MU   = (float*)   alloc((size_t)NB*SC*4);             // 0.5MB
  float*    RS   = (float*)   alloc((size_t)NB*SC*4);             // 0.5MB
  short*    Kd   = (short*)   alloc((size_t)NB*SC*DH*2);          // 32MB
  short*    Vt   = (short*)   alloc((size_t)NB*128*VTILE*2);      // 37.7MB tiled
  short*    AOp  = (short*)   alloc((size_t)NKQ*NB*NQ*DH*2);      // 33.5MB bf16
  float*    ML   = (float*)   alloc((size_t)NKQ*NB*NQ*2*4);       // 1MB
  float*    part = (float*)   alloc((size_t)NB*64*128*4);

  k_cvtw  <<<dim3(256),     dim3(256), 0, stream>>>(wq, wkv, wqb, wkvb);
  k_mask  <<<dim3(16),      dim3(256), 0, stream>>>(mask, bits);
  k_vrow  <<<dim3(32,16),   dim3(256), 0, stream>>>(bits, Vt);
  k_stats <<<dim3(NB*SC/16),dim3(256), 0, stream>>>(xc, MU, RS);
  k_qproj <<<dim3(16),      dim3(256), 0, stream>>>(xq, lnqw, lnqb, wqb, Q0);
  k_kvproj<<<dim3(64,16),   dim3(512), 0, stream>>>(xc, lncw, lncb, wkvb, rc, bits, MU, RS, Kd, Vt);
  k_attn  <<<dim3(1024),    dim3(512), 0, stream>>>(Q0, rq, Kd, Vt, AOp, ML);
  k_fin1  <<<dim3(64,16),   dim3(256), 0, stream>>>(AOp, ML, rq, part);
  k_fin2  <<<dim3(16),      dim3(256), 0, stream>>>(part, wo, bo, out);
}

// Round 17
// 343.358 us; speedup vs baseline: 1.8615x; 1.0887x over previous
//
#include <hip/hip_runtime.h>
#include <hip/hip_bf16.h>

// RotaryCrossAttention on MI355X (gfx950).
// v17 = v14 byte-exact (the empirical optimum: 345us).
//   - k_attn: 8 waves x 16q, 64-key LDS steps (2x16KB K + 2x18KB V, XOR-swz),
//     single barrier/step, kq=4, f32 partials. 32-key variants (v15/v16) are
//     structurally worse: 64B V rows -> 8-way bank conflicts, unswizzlable.
//   - k_kvproj: v11 structure (8 waves, 128-row blocks, K/V wave-pair split).
//     16-row splits (v12/v13) double L2 B-traffic; (512,8) bounds spill.
//   - fin1: 16-q chunks.
// Pipeline: k_cvtw ; k_mask ; k_vrow ; k_stats ; k_qproj ; k_kvproj ;
//           k_attn ; k_fin1 ; k_fin2

#define DEV static __device__ __forceinline__

typedef __attribute__((ext_vector_type(4))) float f32x4;
typedef __attribute__((ext_vector_type(8))) short s16x8;
typedef __attribute__((ext_vector_type(4))) unsigned u32x4;

constexpr int NB   = 16;
constexpr int NQ   = 1024;
constexpr int SC   = 8192;   // T*C
constexpr int DIM  = 512;
constexpr int CDIM = 256;
constexpr int DH   = 128;
constexpr int VTR  = 144;    // V tile rows: d 0..127, row128 = mask-ones, 129..143 dead
constexpr int VTILE = VTR*64; // elems per 64-key V tile (18KB)

DEV short f2bf(float x){
  unsigned u = __builtin_bit_cast(unsigned, x);
  unsigned r = (u + 0x7FFFu + ((u >> 16) & 1u)) >> 16;
  return (short)r;
}

DEV unsigned pk2(float a, float b){
  unsigned short ua = __builtin_bit_cast(unsigned short, __float2bfloat16(a));
  unsigned short ub = __builtin_bit_cast(unsigned short, __float2bfloat16(b));
  return (unsigned)ua | ((unsigned)ub << 16);
}

DEV f32x4 mfma16(s16x8 a, s16x8 b, f32x4 c){
  return __builtin_amdgcn_mfma_f32_16x16x32_bf16(a, b, c, 0, 0, 0);
}

DEV void gload16(const void* g, void* l){
  __builtin_amdgcn_global_load_lds(
      (const __attribute__((address_space(1))) void*)g,
      (__attribute__((address_space(3))) void*)l, 16, 0, 0);
}

// P cross-lane exchange (verified v3): C-layout St rows -> PV B-frag.
DEV s16x8 pexch(int ia0, int ia1, bool hi, unsigned L0, unsigned H0, unsigned L1, unsigned H1){
  int aL0 = __builtin_amdgcn_ds_bpermute(ia0, (int)L0);
  int aL1 = __builtin_amdgcn_ds_bpermute(ia0, (int)L1);
  int aH0 = __builtin_amdgcn_ds_bpermute(ia0, (int)H0);
  int aH1 = __builtin_amdgcn_ds_bpermute(ia0, (int)H1);
  int bL0 = __builtin_amdgcn_ds_bpermute(ia1, (int)L0);
  int bL1 = __builtin_amdgcn_ds_bpermute(ia1, (int)L1);
  int bH0 = __builtin_amdgcn_ds_bpermute(ia1, (int)H0);
  int bH1 = __builtin_amdgcn_ds_bpermute(ia1, (int)H1);
  u32x4 r;
  r[0] = (unsigned)(hi ? aL1 : aL0);
  r[1] = (unsigned)(hi ? aH1 : aH0);
  r[2] = (unsigned)(hi ? bL1 : bL0);
  r[3] = (unsigned)(hi ? bH1 : bH0);
  return __builtin_bit_cast(s16x8, r);
}

// ---------------- weights f32 -> bf16 ----------------
__global__ void k_cvtw(const float* __restrict__ wq, const float* __restrict__ wkv,
                       short* __restrict__ wqb, short* __restrict__ wkvb){
  int i = blockIdx.x * 256 + threadIdx.x;
  if(i < 128*512) wqb[i]  = f2bf(wq[i]);
  if(i < 256*256) wkvb[i] = f2bf(wkv[i]);
}

// ---------------- mask: detect bool(1B) vs int32(4B), pack to bits ----------------
__global__ void k_mask(const unsigned char* __restrict__ raw, unsigned* __restrict__ bits){
  const int b = blockIdx.x, t = threadIdx.x;
  int nz = 0;
  for(int i = t; i < 8192; i += 256){       // first 32KB valid under both layouts
    unsigned w = ((const unsigned*)raw)[i];
    if(w & 0xFFFFFF00u) nz = 1;
  }
  int any = __syncthreads_or(nz);
  bool isInt = (any == 0);
  if(t < 64){
    unsigned out = 0;
    if(isInt){
      const int* p = (const int*)raw + (b*2048 + t*32);
      for(int j = 0; j < 32; j++) out |= (unsigned)(p[j] != 0) << j;
    } else {
      const unsigned char* p = raw + (b*2048 + t*32);
      for(int j = 0; j < 32; j++) out |= (unsigned)(p[j] != 0) << j;
    }
    bits[b*64 + t] = out;
  }
}

// ---------------- V tile row 128 = mask as bf16 ones ----------------
__global__ void k_vrow(const unsigned* __restrict__ bits, short* __restrict__ Vt){
  int b = blockIdx.y;
  int s = blockIdx.x * 256 + threadIdx.x;    // 0..8191
  unsigned w = bits[b*64 + ((s & 2047) >> 5)];
  short v = ((w >> (s & 31)) & 1u) ? (short)0x3F80 : (short)0;
  Vt[(((size_t)b*128 + (s >> 6))*VTR + 128)*64 + (s & 63)] = v;
}

// ---------------- LN stats for context rows: mu/rstd per row ----------------
__global__ __launch_bounds__(256) void k_stats(const float* __restrict__ xc,
                                               float* __restrict__ MU, float* __restrict__ RS){
  const size_t row = (size_t)blockIdx.x * 16 + (threadIdx.x >> 4);   // global row in [0, NB*SC)
  const int cl = (threadIdx.x & 15) * 16;
  const float* rp = xc + row * CDIM + cl;
  float s = 0.f, sq = 0.f;
  #pragma unroll
  for(int i = 0; i < 4; i++){
    f32x4 a = *(const f32x4*)(rp + i*4);
    #pragma unroll
    for(int j = 0; j < 4; j++){ s += a[j]; sq += a[j]*a[j]; }
  }
  #pragma unroll
  for(int o = 8; o > 0; o >>= 1){ s += __shfl_xor(s, o); sq += __shfl_xor(sq, o); }
  if((threadIdx.x & 15) == 0){
    float m = s * (1.f/CDIM);
    MU[row] = m;
    RS[row] = rsqrtf(sq * (1.f/CDIM) - m*m + 1e-5f);
  }
}

// ---------------- Q projection: LN + GEMM (1024x512 @ 512x128) ----------------
__global__ __launch_bounds__(256) void k_qproj(const float* __restrict__ xq,
                                               const float* __restrict__ lnw, const float* __restrict__ lnb,
                                               const short* __restrict__ wqb, float* __restrict__ Q0){
  const int wid = threadIdx.x >> 6, lane = threadIdx.x & 63;
  const int g = lane >> 4, li = lane & 15;
  const int row0 = blockIdx.x * 64 + wid * 16;

  float mean = 0.f, rstd = 0.f;
  #pragma unroll
  for(int r = 0; r < 16; r++){
    const float* rp = xq + (row0 + r) * DIM;
    f32x4 a = *(const f32x4*)(rp + lane*8);
    f32x4 b = *(const f32x4*)(rp + lane*8 + 4);
    float s = 0.f, sq = 0.f;
    #pragma unroll
    for(int i = 0; i < 4; i++){ s += a[i] + b[i]; sq += a[i]*a[i] + b[i]*b[i]; }
    #pragma unroll
    for(int o = 32; o > 0; o >>= 1){ s += __shfl_xor(s, o); sq += __shfl_xor(sq, o); }
    if(li == r){
      mean = s / DIM;
      float var = sq / DIM - mean*mean;
      rstd = rsqrtf(var + 1e-5f);
    }
  }

  f32x4 acc[8];
  #pragma unroll
  for(int n = 0; n < 8; n++) acc[n] = f32x4{0.f,0.f,0.f,0.f};

  for(int kc = 0; kc < 16; kc++){
    int kd = kc*32 + g*8;
    const float* rp = xq + (row0 + li)*DIM + kd;
    f32x4 a0 = *(const f32x4*)rp;
    f32x4 a1 = *(const f32x4*)(rp + 4);
    f32x4 w0 = *(const f32x4*)(lnw + kd), w1 = *(const f32x4*)(lnw + kd + 4);
    f32x4 b0 = *(const f32x4*)(lnb + kd), b1 = *(const f32x4*)(lnb + kd + 4);
    s16x8 af;
    #pragma unroll
    for(int i = 0; i < 4; i++){
      af[i]   = f2bf((a0[i] - mean)*rstd*w0[i] + b0[i]);
      af[i+4] = f2bf((a1[i] - mean)*rstd*w1[i] + b1[i]);
    }
    #pragma unroll
    for(int n = 0; n < 8; n++){
      s16x8 bf = *(const s16x8*)(wqb + (n*16 + li)*DIM + kd);
      acc[n] = mfma16(af, bf, acc[n]);
    }
  }
  #pragma unroll
  for(int n = 0; n < 8; n++)
    #pragma unroll
    for(int r = 0; r < 4; r++){
      int m = row0 + g*4 + r;
      Q0[m*DH + n*16 + li] = acc[n][r];
    }
}

// ---------------- KV projection: 8 waves, K/V tile split across wave pairs (v11) ----------------
// grid (64,16), 512 threads. Wave w<4: K tiles (nt 0-7) for rows [w*32,+32);
// wave w+4: V tiles (nt 8-15) for the same rows.
__global__ __launch_bounds__(512, 4) void k_kvproj(const float* __restrict__ xc,
                                                   const float* __restrict__ lnw, const float* __restrict__ lnb,
                                                   const short* __restrict__ wkvb, const float* __restrict__ rc,
                                                   const unsigned* __restrict__ bits,
                                                   const float* __restrict__ MU, const float* __restrict__ RS,
                                                   short* __restrict__ Kd, short* __restrict__ Vt){
  __shared__ __align__(16) short Klds[128][136];
  __shared__ __align__(16) short Vtlds[128][136];
  const int wid = threadIdx.x >> 6, lane = threadIdx.x & 63;
  const int g = lane >> 4, li = lane & 15;
  const int wk = wid & 3;          // row-group 0..3
  const int isV = wid >> 2;        // 0 = K tiles, 1 = V tiles
  const int b = blockIdx.y;
  const int s0 = blockIdx.x * 128;
  const int ws0 = s0 + wk * 32;

  float mean_s[2], rstd_s[2];
  #pragma unroll
  for(int sub = 0; sub < 2; sub++){
    size_t row = (size_t)b*SC + ws0 + sub*16 + li;
    mean_s[sub] = MU[row];
    rstd_s[sub] = RS[row];
  }

  f32x4 acc[8][2];
  #pragma unroll
  for(int n = 0; n < 8; n++){ acc[n][0] = f32x4{0.f,0.f,0.f,0.f}; acc[n][1] = f32x4{0.f,0.f,0.f,0.f}; }

  for(int kc = 0; kc < 8; kc++){
    int kd = kc*32 + g*8;
    f32x4 w0 = *(const f32x4*)(lnw + kd), w1 = *(const f32x4*)(lnw + kd + 4);
    f32x4 b0 = *(const f32x4*)(lnb + kd), b1 = *(const f32x4*)(lnb + kd + 4);
    s16x8 af[2];
    #pragma unroll
    for(int sub = 0; sub < 2; sub++){
      const float* rp = xc + ((size_t)b*SC + ws0 + sub*16 + li)*CDIM + kd;
      f32x4 a0 = *(const f32x4*)rp;
      f32x4 a1 = *(const f32x4*)(rp + 4);
      float mn = mean_s[sub], rs = rstd_s[sub];
      #pragma unroll
      for(int i = 0; i < 4; i++){
        af[sub][i]   = f2bf((a0[i]-mn)*rs*w0[i] + b0[i]);
        af[sub][i+4] = f2bf((a1[i]-mn)*rs*w1[i] + b1[i]);
      }
    }
    #pragma unroll
    for(int ntl = 0; ntl < 8; ntl++){
      const int nt = isV*8 + ntl;
      s16x8 bf = *(const s16x8*)(wkvb + (nt*16 + li)*CDIM + kd);
      acc[ntl][0] = mfma16(af[0], bf, acc[ntl][0]);
      acc[ntl][1] = mfma16(af[1], bf, acc[ntl][1]);
    }
  }

  // rotary + stage: K-waves -> Klds rows; V-waves -> Vtlds transposed
  if(isV == 0){
    #pragma unroll
    for(int ntl = 0; ntl < 8; ntl++)
      #pragma unroll
      for(int sub = 0; sub < 2; sub++)
        #pragma unroll
        for(int r = 0; r < 4; r++){
          int srow = wk*32 + sub*16 + g*4 + r;       // 0..127
          int d = ntl*16 + li;                       // 0..127
          float f = rc[((size_t)b*SC + s0 + srow)*DH + d];
          float sn, cs; __sincosf(f, &sn, &cs);
          float kv = acc[ntl][sub][r];
          float kp = __shfl_xor(kv, 1);
          float ky = (d & 1) ? (kv*cs + kp*sn) : (kv*cs - kp*sn);
          Klds[srow][d] = f2bf(ky);
        }
  } else {
    #pragma unroll
    for(int ntl = 0; ntl < 8; ntl++)
      #pragma unroll
      for(int sub = 0; sub < 2; sub++)
        #pragma unroll
        for(int r = 0; r < 4; r++){
          int srow = wk*32 + sub*16 + g*4 + r;
          int d = ntl*16 + li;
          float f = rc[((size_t)b*SC + s0 + srow)*DH + d];
          float sn, cs; __sincosf(f, &sn, &cs);
          float vv = acc[ntl][sub][r];
          float vp = __shfl_xor(vv, 1);
          float vy = (d & 1) ? (vv*cs + vp*sn) : (vv*cs - vp*sn);
          Vtlds[d][srow] = f2bf(vy);
        }
  }
  __syncthreads();
  for(int c = threadIdx.x; c < 2048; c += 512){
    int row = c >> 4, col = (c & 15) * 8;
    s16x8 kv = *(const s16x8*)&Klds[row][col];
    *(s16x8*)(Kd + ((size_t)b*SC + s0 + row)*DH + col) = kv;
    s16x8 vv = *(const s16x8*)&Vtlds[row][col];
    int sa = s0 + col;
    unsigned w = bits[b*64 + ((sa & 2047) >> 5)];
    unsigned mb = (w >> (sa & 31)) & 0xFFu;
    #pragma unroll
    for(int j = 0; j < 8; j++) if(!((mb >> j) & 1u)) vv[j] = 0;
    *(s16x8*)(Vt + (((size_t)b*128 + (sa >> 6))*VTR + row)*64 + (sa & 63)) = vv;
  }
}

// ---------------- attention ----------------
// grid 512 = b(16) x qt(8) x kq(4); block = 8 waves x 16 q-rows (128-q tile);
// waves share 64-key LDS steps (double-buffered, XOR-swizzled). Single
// barrier per step: STAGE(t+1) flies during compute on buf cur.
__global__ __launch_bounds__(512, 4) void k_attn(const float* __restrict__ Q0, const float* __restrict__ rq,
                                                 const short* __restrict__ Kd, const short* __restrict__ Vt,
                                                 float* __restrict__ AOp, float* __restrict__ ML){
  __shared__ __align__(16) short Kbuf[2][64*128];   // 2 x 16KB
  __shared__ __align__(16) short Vbuf[2][VTR*64];   // 2 x 18KB
  const int wid = threadIdx.x >> 6, lane = threadIdx.x & 63;
  const int g = lane >> 4, li = lane & 15;
  // XCD-grouped decode: each XCD gets 2 batches, kq-major then q-tiles
  const int xcd = blockIdx.x & 7, ii = blockIdx.x >> 3;
  const int b  = xcd*2 + (ii >> 5);
  const int kq = (ii >> 3) & 3;
  const int qt = ii & 7;
  const int qw0 = qt*128 + wid*16;     // wave owns 16 q rows
  constexpr float C2 = 0.08838834764831845f * 1.4426950408889634f; // scale * log2(e)

  // Q fragment (one 16-q group) with rotary applied, pre-scaled by C2, bf16
  s16x8 qf[4];
  {
    int qrow = qw0 + li;
    #pragma unroll
    for(int c = 0; c < 4; c++){
      int d0 = c*32 + g*8;
      const float* qp = Q0 + qrow*DH + d0;
      const float* fp = rq + ((size_t)b*NQ + qrow)*DH + d0;
      f32x4 x0 = *(const f32x4*)qp,     x1 = *(const f32x4*)(qp+4);
      f32x4 f0 = *(const f32x4*)fp,     f1 = *(const f32x4*)(fp+4);
      float xs[8] = {x0[0],x0[1],x0[2],x0[3],x1[0],x1[1],x1[2],x1[3]};
      float fs[8] = {f0[0],f0[1],f0[2],f0[3],f1[0],f1[1],f1[2],f1[3]};
      #pragma unroll
      for(int i = 0; i < 4; i++){
        float se, ce, so, co;
        __sincosf(fs[2*i],   &se, &ce);
        __sincosf(fs[2*i+1], &so, &co);
        qf[c][2*i]   = f2bf((xs[2*i]*ce   - xs[2*i+1]*se) * C2);
        qf[c][2*i+1] = f2bf((xs[2*i+1]*co + xs[2*i]*so) * C2);
      }
    }
  }

  float mrun = -1e30f;
  f32x4 acc[9];
  #pragma unroll
  for(int dt = 0; dt < 9; dt++) acc[dt] = f32x4{0.f,0.f,0.f,0.f};

  const char* Kg = (const char*)(Kd + ((size_t)b*SC + kq*2048)*DH);   // 256B rows
  const char* Vg = (const char*)(Vt + ((size_t)b*128 + kq*32)*VTILE); // 18KB tiles

  const int ia0 = (((lane >> 4) & 1) * 32 + li) << 2;
  const int ia1 = ia0 + 64;
  const bool hi = (g >= 2);

  // staging, 8-way split: wave stages K rows [wid*8,+8) (2 issues of 4 rows)
  // and V rows [wid*16,+16) (2 issues of 8 rows); waves 0,1 also stage V rows
  // 128..143 (one extra issue each).
  #define STAGE(bufi, t) do{                                                   \
    const char* Ksrc = Kg + (size_t)(t)*64*256;                                \
    _Pragma("unroll")                                                          \
    for(int j = 0; j < 2; j++){                                                \
      int rp = wid*8 + j*4 + (lane >> 4);                                      \
      int bi = ((lane & 15)*16) ^ ((rp & 7) << 4);                             \
      gload16(Ksrc + rp*256 + bi, &Kbuf[bufi][(wid*8 + j*4)*128]);             \
    }                                                                          \
    const char* Vsrc = Vg + (size_t)(t)*VTILE*2;                               \
    _Pragma("unroll")                                                          \
    for(int j = 0; j < 2; j++){                                                \
      int rp = wid*16 + j*8 + (lane >> 3);                                     \
      int bi = ((lane & 7)*16) ^ ((rp & 7) << 4);                              \
      gload16(Vsrc + rp*128 + bi, &Vbuf[bufi][(wid*16 + j*8)*64]);             \
    }                                                                          \
    if(wid < 2){                                                               \
      int rp = 128 + wid*8 + (lane >> 3);                                      \
      int bi = ((lane & 7)*16) ^ ((rp & 7) << 4);                              \
      gload16(Vsrc + rp*128 + bi, &Vbuf[bufi][(128 + wid*8)*64]);              \
    }                                                                          \
  }while(0)

  STAGE(0, 0);
  __syncthreads();                     // prologue: buf0 staged & visible

  for(int t = 0; t < 32; ++t){
    const int cur = t & 1;
    if(t < 31) STAGE(cur^1, t+1);      // loads stay in flight during compute

    // QK: St[k, q] for 64 keys
    f32x4 st[4];
    __builtin_amdgcn_s_setprio(1);
    #pragma unroll
    for(int ks = 0; ks < 4; ks++){
      s16x8 kf[4];
      #pragma unroll
      for(int c = 0; c < 4; c++){
        int row = ks*16 + li;
        int off = row*256 + ((c*64 + g*16) ^ ((row & 7) << 4));
        kf[c] = *(const s16x8*)((const char*)&Kbuf[cur][0] + off);
      }
      f32x4 s = f32x4{0.f,0.f,0.f,0.f};
      #pragma unroll
      for(int c = 0; c < 4; c++) s = mfma16(kf[c], qf[c], s);
      st[ks] = s;
    }
    __builtin_amdgcn_s_setprio(0);

    // softmax + P B-frags
    s16x8 pf[2];
    {
      float mt = -1e30f;
      #pragma unroll
      for(int ks = 0; ks < 4; ks++)
        #pragma unroll
        for(int r = 0; r < 4; r++) mt = fmaxf(mt, st[ks][r]);
      mt = fmaxf(mt, __shfl_xor(mt, 16));
      mt = fmaxf(mt, __shfl_xor(mt, 32));
      if(__any(mt > mrun + 3.0f)){          // defer-rescale
        float mnew = fmaxf(mrun, mt);
        float a = exp2f(mrun - mnew);
        mrun = mnew;
        #pragma unroll
        for(int dt = 0; dt < 9; dt++) acc[dt] = acc[dt] * a;
      }
      float m = mrun;
      #pragma unroll
      for(int h2 = 0; h2 < 2; h2++){
        unsigned L0 = pk2(exp2f(st[2*h2][0] - m),   exp2f(st[2*h2][1] - m));
        unsigned H0 = pk2(exp2f(st[2*h2][2] - m),   exp2f(st[2*h2][3] - m));
        unsigned L1 = pk2(exp2f(st[2*h2+1][0] - m), exp2f(st[2*h2+1][1] - m));
        unsigned H1 = pk2(exp2f(st[2*h2+1][2] - m), exp2f(st[2*h2+1][3] - m));
        pf[h2] = pexch(ia0, ia1, hi, L0, H0, L1, H1);
      }
    }

    // PV: acc^T[d, q] += V^T-tile x P
    __builtin_amdgcn_s_setprio(1);
    #pragma unroll
    for(int dt = 0; dt < 9; dt++){
      int row = dt*16 + li;
      #pragma unroll
      for(int k32 = 0; k32 < 2; k32++){
        int off = row*128 + ((k32*64 + g*16) ^ ((row & 7) << 4));
        s16x8 vf = *(const s16x8*)((const char*)&Vbuf[cur][0] + off);
        acc[dt] = mfma16(vf, pf[k32], acc[dt]);
      }
    }
    __builtin_amdgcn_s_setprio(0);

    __syncthreads();   // drains the t+1 loads (they flew during compute);
                       // also: all reads of cur done before t+2 re-stages it
  }

  // epilogue: each wave writes its own 16 q rows (partial O, m, l)
  const size_t pbase = ((size_t)kq*NB + b)*NQ;
  if(lane < 16){
    size_t o = pbase + qw0 + li;
    ML[o*2]   = mrun;
    ML[o*2+1] = acc[8][0];
  }
  {
    size_t o = (pbase + qw0 + li)*DH;
    #pragma unroll
    for(int dt = 0; dt < 8; dt++)
      *(f32x4*)(AOp + o + dt*16 + g*4) = acc[dt];
  }
}

// ---------------- final part 1: merge 4 key-quarters + inverse rotary + partial mean ----------------
// grid (64,16): 16 queries per chunk for TLP.
__global__ __launch_bounds__(256) void k_fin1(const float* __restrict__ AOp, const float* __restrict__ ML,
                                              const float* __restrict__ rq, float* __restrict__ part){
  __shared__ float red[2][128];
  const int b = blockIdx.y, ch = blockIdx.x;
  const int t = threadIdx.x;
  const int d = t & 127, h = t >> 7;
  float acc = 0.f;
  #pragma unroll 2
  for(int i = 0; i < 8; i++){
    int n = ch*16 + h*8 + i;
    size_t qi = (size_t)b*NQ + n;
    float m[4], l[4];
    #pragma unroll
    for(int kq = 0; kq < 4; kq++){
      size_t o = (size_t)kq*NB*NQ + qi;
      m[kq] = ML[o*2]; l[kq] = ML[o*2+1];
    }
    float M = fmaxf(fmaxf(m[0], m[1]), fmaxf(m[2], m[3]));
    float w[4], L = 0.f;
    #pragma unroll
    for(int kq = 0; kq < 4; kq++){ w[kq] = exp2f(m[kq] - M); L += w[kq]*l[kq]; }
    float inv = 1.f / L;
    float O = 0.f;
    #pragma unroll
    for(int kq = 0; kq < 4; kq++) O += w[kq]*AOp[((size_t)kq*NB*NQ + qi)*DH + d];
    O *= inv;
    float P = __shfl_xor(O, 1);
    float f = rq[qi*DH + d];
    float sn, cs; __sincosf(f, &sn, &cs);
    acc += (d & 1) ? (O*cs - P*sn) : (O*cs + P*sn);   // rotary with -f
  }
  red[h][d] = acc;
  __syncthreads();
  if(h == 0) part[((size_t)b*64 + ch)*128 + d] = red[0][d] + red[1][d];
}

// ---------------- final part 2: reduce chunks + @ w_o^T + b_o ----------------
__global__ __launch_bounds__(256) void k_fin2(const float* __restrict__ part,
                                              const float* __restrict__ wo, const float* __restrict__ bo,
                                              float* __restrict__ out){
  __shared__ float sm[128];
  const int b = blockIdx.x, t = threadIdx.x;
  if(t < 128){
    float s = 0.f;
    for(int ch = 0; ch < 64; ch++) s += part[((size_t)b*64 + ch)*128 + t];
    sm[t] = s * (1.0f / NQ);
  }
  __syncthreads();
  for(int o = t; o < DIM; o += 256){
    float s = bo[o];
    const float* wr = wo + o*DH;
    #pragma unroll 4
    for(int j = 0; j < DH; j++) s += sm[j] * wr[j];
    out[b*DIM + o] = s;
  }
}

extern "C" void kernel_launch(void* const* d_in, const int* in_sizes, int n_in,
                              void* d_out, int out_size, void* d_ws, size_t ws_size,
                              hipStream_t stream){
  const float* xq   = (const float*)d_in[0];
  const float* xc   = (const float*)d_in[1];
  const float* rq   = (const float*)d_in[2];
  const float* rc   = (const float*)d_in[3];
  const unsigned char* mask = (const unsigned char*)d_in[4];
  const float* lnqw = (const float*)d_in[5];
  const float* lnqb = (const float*)d_in[6];
  const float* lncw = (const float*)d_in[7];
  const float* lncb = (const float*)d_in[8];
  const float* wq   = (const float*)d_in[9];
  const float* wkv  = (const float*)d_in[10];
  const float* wo   = (const float*)d_in[11];
  const float* bo   = (const float*)d_in[12];
  float* out = (float*)d_out;

  char* ws = (char*)d_ws;
  size_t off = 0;
  auto alloc = [&](size_t bytes){ void* p = ws + off; off += (bytes + 255) & ~(size_t)255; return p; };
  float*    Q0   = (float*)   alloc((size_t)NQ*DH*4);
  short*    wqb  = (short*)   alloc((size_t)128*512*2);
  short*    wkvb = (short*)   alloc((size_t)256*256*2);
  unsigned* bits = (unsigned*)alloc((size_t)NB*64*4);
  float*    MU   = (float*)   alloc((size_t)NB*SC*4);             // 0.5MB
  float*    RS   = (float*)   alloc((size_t)NB*SC*4);             // 0.5MB
  short*    Kd   = (short*)   alloc((size_t)NB*SC*DH*2);          // 32MB
  short*    Vt   = (short*)   alloc((size_t)NB*128*VTILE*2);      // 37.7MB tiled
  float*    AOp  = (float*)   alloc((size_t)4*NB*NQ*DH*4);        // 33.5MB
  float*    ML   = (float*)   alloc((size_t)4*NB*NQ*2*4);
  float*    part = (float*)   alloc((size_t)NB*64*128*4);

  k_cvtw  <<<dim3(256),     dim3(256), 0, stream>>>(wq, wkv, wqb, wkvb);
  k_mask  <<<dim3(16),      dim3(256), 0, stream>>>(mask, bits);
  k_vrow  <<<dim3(32,16),   dim3(256), 0, stream>>>(bits, Vt);
  k_stats <<<dim3(NB*SC/16),dim3(256), 0, stream>>>(xc, MU, RS);
  k_qproj <<<dim3(16),      dim3(256), 0, stream>>>(xq, lnqw, lnqb, wqb, Q0);
  k_kvproj<<<dim3(64,16),   dim3(512), 0, stream>>>(xc, lncw, lncb, wkvb, rc, bits, MU, RS, Kd, Vt);
  k_attn  <<<dim3(512),     dim3(512), 0, stream>>>(Q0, rq, Kd, Vt, AOp, ML);
  k_fin1  <<<dim3(64,16),   dim3(256), 0, stream>>>(AOp, ML, rq, part);
  k_fin2  <<<dim3(16),      dim3(256), 0, stream>>>(part, wo, bo, out);
}